// Round 6
// baseline (255.426 us; speedup 1.0000x reference)
//
#include <hip/hip_runtime.h>
#include <cstddef>
#include <cstdint>

#define NH 16
#define HD 64
#define SLEN 1024
#define NB 64
#define DMODEL 1024

#define DOT4_ACC(acc, k, q) \
  acc = fmaf((k).x, (q).x, fmaf((k).y, (q).y, fmaf((k).z, (q).z, fmaf((k).w, (q).w, (acc)))))

#define FMA4_BCAST(accv, qv, w0_, w1_, w2_, w3_) do { \
  (accv).x = fmaf((qv).x, (w0_).x, fmaf((qv).y, (w1_).x, fmaf((qv).z, (w2_).x, fmaf((qv).w, (w3_).x, (accv).x)))); \
  (accv).y = fmaf((qv).x, (w0_).y, fmaf((qv).y, (w1_).y, fmaf((qv).z, (w2_).y, fmaf((qv).w, (w3_).y, (accv).y)))); \
  (accv).z = fmaf((qv).x, (w0_).z, fmaf((qv).y, (w1_).z, fmaf((qv).z, (w2_).z, fmaf((qv).w, (w3_).z, (accv).z)))); \
  (accv).w = fmaf((qv).x, (w0_).w, fmaf((qv).y, (w1_).w, fmaf((qv).z, (w2_).w, fmaf((qv).w, (w3_).w, (accv).w)))); \
} while (0)

__device__ __forceinline__ float wred_sum(float v) {
#pragma unroll
  for (int off = 32; off; off >>= 1) v += __shfl_xor(v, off, 64);
  return v;
}

// Async global->LDS, 16B per lane. LDS dest is wave-uniform base + lane*16;
// global source address is per-lane.
__device__ __forceinline__ void gload16(const float* g, float* lds_base) {
  __builtin_amdgcn_global_load_lds(
      (const __attribute__((address_space(1))) void*)g,
      (__attribute__((address_space(3))) void*)lds_base, 16, 0, 0);
}

// K0: qp[b][j] = sum_c query[b][c] * Wq[j][c].
__global__ __launch_bounds__(256) void k0_qp(const float* __restrict__ query,
                                             const float* __restrict__ Wq,
                                             float* __restrict__ qp) {
  const int tid = threadIdx.x;
  const int w = tid >> 6, l = tid & 63;
  const int j = blockIdx.x * 4 + w;  // 0..1023
  const float4* wr = reinterpret_cast<const float4*>(Wq + (size_t)j * DMODEL) + l * 4;
  const float4 w0 = wr[0], w1 = wr[1], w2 = wr[2], w3 = wr[3];
  for (int b = 0; b < NB; ++b) {
    const float4* qr = reinterpret_cast<const float4*>(query + (size_t)b * DMODEL) + l * 4;
    float4 q0 = qr[0], q1 = qr[1], q2 = qr[2], q3 = qr[3];
    float s = 0.f;
    DOT4_ACC(s, w0, q0); DOT4_ACC(s, w1, q1); DOT4_ACC(s, w2, q2); DOT4_ACC(s, w3, q3);
    s = wred_sum(s);
    if (l == 0) qp[(size_t)b * DMODEL + j] = s;
  }
}

// K1: qt[b][h][m] = sum_d qp[b][h*64+d] * Wk[h*64+d][m].
__global__ __launch_bounds__(256) void k1_qt(const float* __restrict__ qp,
                                             const float* __restrict__ Wk,
                                             float* __restrict__ qt) {
  __shared__ __align__(16) float qpl[8][HD];
  const int h = blockIdx.x & 15;
  const int b0 = (blockIdx.x >> 4) * 8;
  const int tid = threadIdx.x;
  for (int f = tid; f < 8 * HD; f += 256) {
    int bi = f >> 6, d = f & 63;
    qpl[bi][d] = qp[(size_t)(b0 + bi) * DMODEL + h * HD + d];
  }
  __syncthreads();
  const int m4 = tid * 4;
  float4 acc[8];
#pragma unroll
  for (int i = 0; i < 8; ++i) acc[i] = make_float4(0.f, 0.f, 0.f, 0.f);
  const float* wbase = Wk + (size_t)(h * HD) * DMODEL + m4;
  for (int d = 0; d < HD; d += 4) {
    float4 wk0 = *reinterpret_cast<const float4*>(wbase + (size_t)(d + 0) * DMODEL);
    float4 wk1 = *reinterpret_cast<const float4*>(wbase + (size_t)(d + 1) * DMODEL);
    float4 wk2 = *reinterpret_cast<const float4*>(wbase + (size_t)(d + 2) * DMODEL);
    float4 wk3 = *reinterpret_cast<const float4*>(wbase + (size_t)(d + 3) * DMODEL);
#pragma unroll
    for (int bi = 0; bi < 8; ++bi) {
      float4 q = *reinterpret_cast<const float4*>(&qpl[bi][d]);
      FMA4_BCAST(acc[bi], q, wk0, wk1, wk2, wk3);
    }
  }
#pragma unroll
  for (int bi = 0; bi < 8; ++bi)
    *reinterpret_cast<float4*>(qt + ((size_t)(b0 + bi) * NH + h) * DMODEL + m4) = acc[bi];
}

// K2 v6: partial scores over an m-half, keys staged via async global_load_lds.
// Block = 128 thr = (b, st: 128 s-tile, mh: m-half).
// LDS: ql[16][512] (32 KB) + kb[128 rows][16 floats] (8 KB) = 40 KB -> 4 blk/CU.
// Per chunk ch (16 m-words): stage all 128 rows' chunk (8 KB, 4 gload16/wave ->
// deep in-flight queue), barrier, compute, barrier. kb is XOR-swizzled at
// float4 granularity via PRE-SWIZZLED GLOBAL addresses (LDS dest stays linear):
// stored[row][j] = src[row][j ^ (row&3)]; read slot = hg ^ (s&3) -> 8 accesses
// per bank per wave read = conflict-free minimum.
__global__ __launch_bounds__(128) void k2_scores(const float* __restrict__ keys,
                                                 const float* __restrict__ qt,
                                                 float* __restrict__ scp) {
  __shared__ __align__(16) float ql[NH][512];   // 32 KB
  __shared__ __align__(16) float kb[128 * 16];  // 8 KB
  const int b  = blockIdx.x & 63;
  const int st = (blockIdx.x >> 6) & 7;   // 0..7
  const int mh = blockIdx.x >> 9;         // 0..1
  const int tid = threadIdx.x, w = tid >> 6, l = tid & 63;
  const int hg = l & 3;                   // m-quad stripe
  const int sg = l >> 2;                  // 0..15
  // stage q half (16 heads x 512 m) into LDS
  for (int f = tid; f < NH * 128; f += 128) {
    int hh = f >> 7, m4 = (f & 127) * 4;
    *reinterpret_cast<float4*>(&ql[hh][m4]) = *reinterpret_cast<const float4*>(
        qt + ((size_t)b * NH + hh) * DMODEL + mh * 512 + m4);
  }
  const int s0 = st * 128;
  const size_t rowstride = (size_t)NB * DMODEL;
  const float* kbase = keys + ((size_t)s0 * NB + b) * DMODEL + mh * 512;
  // per-lane stage geometry: 16 rows per instr, 4 lanes (16B slots) per row
  const int srow  = l >> 2;                    // row offset within 16-row unit
  const int sslot = (l & 3) ^ (srow & 3);      // pre-swizzled source slot
  float acc[4][NH];
#pragma unroll
  for (int si = 0; si < 4; ++si)
#pragma unroll
    for (int hh = 0; hh < NH; ++hh) acc[si][hh] = 0.f;
  const int sl0 = w * 64 + sg;  // local s = sl0 + si*16

  for (int ch = 0; ch < 32; ++ch) {
    // stage chunk ch for all 128 rows (wave w: units w*4..w*4+3)
#pragma unroll
    for (int i = 0; i < 4; ++i) {
      const int u = w * 4 + i;                 // 0..7
      const int row = u * 16 + srow;           // 0..127
      const float* g = kbase + (size_t)row * rowstride + ch * 16 + sslot * 4;
      gload16(g, &kb[u * 256]);
    }
    __syncthreads();  // drains vmcnt -> chunk resident; also syncs ql on ch==0
    float4 kv[4];
#pragma unroll
    for (int si = 0; si < 4; ++si) {
      const int s = sl0 + si * 16;
      kv[si] = *reinterpret_cast<const float4*>(&kb[s * 16 + ((hg ^ (s & 3)) << 2)]);
    }
#pragma unroll
    for (int hh = 0; hh < NH; ++hh) {
      float4 q = *reinterpret_cast<const float4*>(&ql[hh][ch * 16 + hg * 4]);
      DOT4_ACC(acc[0][hh], kv[0], q);
      DOT4_ACC(acc[1][hh], kv[1], q);
      DOT4_ACC(acc[2][hh], kv[2], q);
      DOT4_ACC(acc[3][hh], kv[3], q);
    }
    __syncthreads();  // protect kb before next stage
  }
  // fold the 4 m-stripes within each lane-quad
#pragma unroll
  for (int si = 0; si < 4; ++si)
#pragma unroll
    for (int hh = 0; hh < NH; ++hh) {
      acc[si][hh] += __shfl_xor(acc[si][hh], 1, 64);
      acc[si][hh] += __shfl_xor(acc[si][hh], 2, 64);
    }
  const float scale = 0.125f;  // 1/sqrt(64); linear -> distributes over m-halves
  float* plane = scp + (size_t)mh * NB * NH * SLEN;
#pragma unroll
  for (int j = 0; j < 4; ++j) {
#pragma unroll
    for (int si = 0; si < 4; ++si) {
      float r = hg == 0 ? acc[si][j] : hg == 1 ? acc[si][4 + j]
              : hg == 2 ? acc[si][8 + j] : acc[si][12 + j];
      plane[((size_t)b * NH + hg * 4 + j) * SLEN + s0 + sl0 + si * 16] = r * scale;
    }
  }
}

// Softmax over s: sums the two partial-score planes, softmax, writes plane0.
__global__ __launch_bounds__(256) void k_sm(float* __restrict__ sc0,
                                            const float* __restrict__ sc1) {
  __shared__ float red[8];
  const int tid = threadIdx.x, w = tid >> 6, l = tid & 63;
  float* p0 = sc0 + (size_t)blockIdx.x * SLEN;
  const float* p1 = sc1 + (size_t)blockIdx.x * SLEN;
  float4 xa = reinterpret_cast<const float4*>(p0)[tid];
  float4 xb = reinterpret_cast<const float4*>(p1)[tid];
  float4 x = make_float4(xa.x + xb.x, xa.y + xb.y, xa.z + xb.z, xa.w + xb.w);
  float mx = fmaxf(fmaxf(x.x, x.y), fmaxf(x.z, x.w));
#pragma unroll
  for (int off = 32; off; off >>= 1) mx = fmaxf(mx, __shfl_xor(mx, off, 64));
  if (l == 0) red[w] = mx;
  __syncthreads();
  mx = fmaxf(fmaxf(red[0], red[1]), fmaxf(red[2], red[3]));
  float4 e;
  e.x = __expf(x.x - mx); e.y = __expf(x.y - mx);
  e.z = __expf(x.z - mx); e.w = __expf(x.w - mx);
  float sum = e.x + e.y + e.z + e.w;
  sum = wred_sum(sum);
  if (l == 0) red[4 + w] = sum;
  __syncthreads();
  sum = red[4] + red[5] + red[6] + red[7];
  const float inv = 1.f / sum;
  e.x *= inv; e.y *= inv; e.z *= inv; e.w *= inv;
  reinterpret_cast<float4*>(p0)[tid] = e;
}

// K3 v6: partial c[ch][b][h][m] = sum_{s in chunk} attn[b][h][s]*values[s][b][m].
// Values staged 4 full rows at a time via global_load_lds (16 KB/group in
// flight per block); attn chunk in LDS (broadcast reads). 256 thr, 4 blk/CU.
template <int NCH>
__global__ __launch_bounds__(256) void k3_cpart(const float* __restrict__ values,
                                                const float* __restrict__ attn,
                                                float* __restrict__ cp) {
  constexpr int SC = SLEN / NCH;
  __shared__ __align__(16) float vb[4][DMODEL];  // 16 KB
  __shared__ __align__(16) float al[NH][SC];
  const int b = blockIdx.x & 63;
  const int ch = blockIdx.x >> 6;
  const int s0 = ch * SC;
  const int tid = threadIdx.x, w = tid >> 6, l = tid & 63;
  for (int f = tid; f < NH * (SC / 4); f += 256) {
    int hh = f / (SC / 4), c4 = (f % (SC / 4)) * 4;
    *reinterpret_cast<float4*>(&al[hh][c4]) = *reinterpret_cast<const float4*>(
        attn + ((size_t)b * NH + hh) * SLEN + s0 + c4);
  }
  const int m4 = tid * 4;
  float4 acc[NH];
#pragma unroll
  for (int i = 0; i < NH; ++i) acc[i] = make_float4(0.f, 0.f, 0.f, 0.f);
  const size_t rowstride = (size_t)NB * DMODEL;
  const float* vbase = values + ((size_t)s0 * NB + b) * DMODEL;

  for (int g = 0; g < SC / 4; ++g) {
    // wave w stages row g*4+w (4 quarter-row gload16s, 1 KB each)
    {
      const float* rg = vbase + (size_t)(g * 4 + w) * rowstride;
#pragma unroll
      for (int j = 0; j < 4; ++j)
        gload16(rg + j * 256 + l * 4, &vb[w][j * 256]);
    }
    __syncthreads();  // drains vmcnt -> rows resident; also syncs al on g==0
    float4 v0 = *reinterpret_cast<const float4*>(&vb[0][m4]);
    float4 v1 = *reinterpret_cast<const float4*>(&vb[1][m4]);
    float4 v2 = *reinterpret_cast<const float4*>(&vb[2][m4]);
    float4 v3 = *reinterpret_cast<const float4*>(&vb[3][m4]);
#pragma unroll
    for (int hh = 0; hh < NH; ++hh) {
      float4 av = *reinterpret_cast<const float4*>(&al[hh][g * 4]);  // broadcast
      FMA4_BCAST(acc[hh], av, v0, v1, v2, v3);
    }
    __syncthreads();  // protect vb before next stage
  }
#pragma unroll
  for (int hh = 0; hh < NH; ++hh)
    *reinterpret_cast<float4*>(cp + (((size_t)ch * NB + b) * NH + hh) * DMODEL + m4) = acc[hh];
}

// K4: out[b][h*64+d] = sum_m Wk[h*64+d][m] * (sum_ch cp[ch][b][h][m]).
template <int NCH>
__global__ __launch_bounds__(256) void k4_out(const float* __restrict__ cp,
                                              const float* __restrict__ Wk,
                                              float* __restrict__ out) {
  __shared__ __align__(16) float cl[4 * DMODEL];
  const int h = blockIdx.x & 15;
  const int b0 = (blockIdx.x >> 4) * 4;
  const int tid = threadIdx.x, w = tid >> 6, l = tid & 63;
  for (int f = tid; f < 4 * DMODEL / 4; f += 256) {
    int bi = f >> 8, m4 = (f & 255) * 4;
    float4 s = make_float4(0.f, 0.f, 0.f, 0.f);
#pragma unroll
    for (int ch = 0; ch < NCH; ++ch) {
      float4 t = *reinterpret_cast<const float4*>(
          cp + (((size_t)ch * NB + b0 + bi) * NH + h) * DMODEL + m4);
      s.x += t.x; s.y += t.y; s.z += t.z; s.w += t.w;
    }
    *reinterpret_cast<float4*>(&cl[bi * DMODEL + m4]) = s;
  }
  __syncthreads();
  float4 c[4][4];
#pragma unroll
  for (int bi = 0; bi < 4; ++bi)
#pragma unroll
    for (int k = 0; k < 4; ++k)
      c[bi][k] = *reinterpret_cast<const float4*>(&cl[bi * DMODEL + l * 16 + k * 4]);
  for (int jj = 0; jj < 16; ++jj) {
    const int d = w * 16 + jj;
    const float4* wr = reinterpret_cast<const float4*>(Wk + (size_t)(h * HD + d) * DMODEL) + l * 4;
    const float4 w0 = wr[0], w1 = wr[1], w2 = wr[2], w3 = wr[3];
#pragma unroll
    for (int bi = 0; bi < 4; ++bi) {
      float s = 0.f;
      DOT4_ACC(s, w0, c[bi][0]); DOT4_ACC(s, w1, c[bi][1]);
      DOT4_ACC(s, w2, c[bi][2]); DOT4_ACC(s, w3, c[bi][3]);
      s = wred_sum(s);
      if (l == 0) out[(size_t)(b0 + bi) * (NH * HD) + h * HD + d] = s;
    }
  }
}

extern "C" void kernel_launch(void* const* d_in, const int* in_sizes, int n_in,
                              void* d_out, int out_size, void* d_ws, size_t ws_size,
                              hipStream_t stream) {
  const float* query  = (const float*)d_in[0];
  const float* keys   = (const float*)d_in[1];
  const float* values = (const float*)d_in[2];
  const float* Wq     = (const float*)d_in[3];
  const float* Wk     = (const float*)d_in[4];
  float* out = (float*)d_out;

  float* W   = (float*)d_ws;
  float* qp  = W;                                   // 64*1024
  float* qt  = qp + (size_t)NB * DMODEL;            // 64*16*1024
  float* sc0 = qt + (size_t)NB * NH * DMODEL;       // partial m-half 0 -> attn
  float* sc1 = sc0 + (size_t)NB * NH * SLEN;        // partial m-half 1
  float* cp  = sc1 + (size_t)NB * NH * SLEN;        // NCH*64*16*1024

  const size_t base_floats = (size_t)NB * DMODEL + (size_t)NB * NH * DMODEL
                           + 2 * (size_t)NB * NH * SLEN;

  k0_qp<<<256, 256, 0, stream>>>(query, Wq, qp);
  k1_qt<<<128, 256, 0, stream>>>(qp, Wk, qt);
  k2_scores<<<1024, 128, 0, stream>>>(keys, qt, sc0);  // writes sc0 (mh=0) and sc1 (mh=1)
  k_sm<<<NB * NH, 256, 0, stream>>>(sc0, sc1);

  const size_t chunk_floats = (size_t)NB * NH * DMODEL;
  if (ws_size >= (base_floats + 16 * chunk_floats) * sizeof(float)) {
    k3_cpart<16><<<16 * NB, 256, 0, stream>>>(values, sc0, cp);
    k4_out<16><<<NH * (NB / 4), 256, 0, stream>>>(cp, Wk, out);
  } else if (ws_size >= (base_floats + 8 * chunk_floats) * sizeof(float)) {
    k3_cpart<8><<<8 * NB, 256, 0, stream>>>(values, sc0, cp);
    k4_out<8><<<NH * (NB / 4), 256, 0, stream>>>(cp, Wk, out);
  } else {
    k3_cpart<4><<<4 * NB, 256, 0, stream>>>(values, sc0, cp);
    k4_out<4><<<NH * (NB / 4), 256, 0, stream>>>(cp, Wk, out);
  }
}

// Round 7
// 250.155 us; speedup vs baseline: 1.0211x; 1.0211x over previous
//
#include <hip/hip_runtime.h>
#include <cstddef>
#include <cstdint>

#define NH 16
#define HD 64
#define SLEN 1024
#define NB 64
#define DMODEL 1024

#define DOT4_ACC(acc, k, q) \
  acc = fmaf((k).x, (q).x, fmaf((k).y, (q).y, fmaf((k).z, (q).z, fmaf((k).w, (q).w, (acc)))))

#define FMA4_BCAST(accv, qv, w0_, w1_, w2_, w3_) do { \
  (accv).x = fmaf((qv).x, (w0_).x, fmaf((qv).y, (w1_).x, fmaf((qv).z, (w2_).x, fmaf((qv).w, (w3_).x, (accv).x)))); \
  (accv).y = fmaf((qv).x, (w0_).y, fmaf((qv).y, (w1_).y, fmaf((qv).z, (w2_).y, fmaf((qv).w, (w3_).y, (accv).y)))); \
  (accv).z = fmaf((qv).x, (w0_).z, fmaf((qv).y, (w1_).z, fmaf((qv).z, (w2_).z, fmaf((qv).w, (w3_).z, (accv).z)))); \
  (accv).w = fmaf((qv).x, (w0_).w, fmaf((qv).y, (w1_).w, fmaf((qv).z, (w2_).w, fmaf((qv).w, (w3_).w, (accv).w)))); \
} while (0)

__device__ __forceinline__ float wred_sum(float v) {
#pragma unroll
  for (int off = 32; off; off >>= 1) v += __shfl_xor(v, off, 64);
  return v;
}

// Async global->LDS, 16B per lane. LDS dest = wave-uniform base + lane*16;
// global source address is per-lane.
__device__ __forceinline__ void gload16(const float* g, float* lds_base) {
  __builtin_amdgcn_global_load_lds(
      (const __attribute__((address_space(1))) void*)g,
      (__attribute__((address_space(3))) void*)lds_base, 16, 0, 0);
}

// K0: qp[b][j] = sum_c query[b][c] * Wq[j][c].
__global__ __launch_bounds__(256) void k0_qp(const float* __restrict__ query,
                                             const float* __restrict__ Wq,
                                             float* __restrict__ qp) {
  const int tid = threadIdx.x;
  const int w = tid >> 6, l = tid & 63;
  const int j = blockIdx.x * 4 + w;  // 0..1023
  const float4* wr = reinterpret_cast<const float4*>(Wq + (size_t)j * DMODEL) + l * 4;
  const float4 w0 = wr[0], w1 = wr[1], w2 = wr[2], w3 = wr[3];
  for (int b = 0; b < NB; ++b) {
    const float4* qr = reinterpret_cast<const float4*>(query + (size_t)b * DMODEL) + l * 4;
    float4 q0 = qr[0], q1 = qr[1], q2 = qr[2], q3 = qr[3];
    float s = 0.f;
    DOT4_ACC(s, w0, q0); DOT4_ACC(s, w1, q1); DOT4_ACC(s, w2, q2); DOT4_ACC(s, w3, q3);
    s = wred_sum(s);
    if (l == 0) qp[(size_t)b * DMODEL + j] = s;
  }
}

// K1: qt[b][h][m] = sum_d qp[b][h*64+d] * Wk[h*64+d][m].
__global__ __launch_bounds__(256) void k1_qt(const float* __restrict__ qp,
                                             const float* __restrict__ Wk,
                                             float* __restrict__ qt) {
  __shared__ __align__(16) float qpl[8][HD];
  const int h = blockIdx.x & 15;
  const int b0 = (blockIdx.x >> 4) * 8;
  const int tid = threadIdx.x;
  for (int f = tid; f < 8 * HD; f += 256) {
    int bi = f >> 6, d = f & 63;
    qpl[bi][d] = qp[(size_t)(b0 + bi) * DMODEL + h * HD + d];
  }
  __syncthreads();
  const int m4 = tid * 4;
  float4 acc[8];
#pragma unroll
  for (int i = 0; i < 8; ++i) acc[i] = make_float4(0.f, 0.f, 0.f, 0.f);
  const float* wbase = Wk + (size_t)(h * HD) * DMODEL + m4;
  for (int d = 0; d < HD; d += 4) {
    float4 wk0 = *reinterpret_cast<const float4*>(wbase + (size_t)(d + 0) * DMODEL);
    float4 wk1 = *reinterpret_cast<const float4*>(wbase + (size_t)(d + 1) * DMODEL);
    float4 wk2 = *reinterpret_cast<const float4*>(wbase + (size_t)(d + 2) * DMODEL);
    float4 wk3 = *reinterpret_cast<const float4*>(wbase + (size_t)(d + 3) * DMODEL);
#pragma unroll
    for (int bi = 0; bi < 8; ++bi) {
      float4 q = *reinterpret_cast<const float4*>(&qpl[bi][d]);
      FMA4_BCAST(acc[bi], q, wk0, wk1, wk2, wk3);
    }
  }
#pragma unroll
  for (int bi = 0; bi < 8; ++bi)
    *reinterpret_cast<float4*>(qt + ((size_t)(b0 + bi) * NH + h) * DMODEL + m4) = acc[bi];
}

// K2 v7: partial scores over an m-half, DOUBLE-BUFFERED async staging.
// Block = 128 thr = (b, st: 128-s tile, mh: m-half). Per 16-m-word chunk:
// issue next chunk's global_load_lds into buf^1 BEFORE computing buf, one
// barrier per chunk (T3-minimum 2-phase; loads stay in flight across compute).
// LDS: kb 2x8KB + qb 2x1KB = 18.5 KB. kb XOR-swizzled via pre-swizzled global
// source (LDS dest linear); read slot = hg^(s&3). Same indexing as verified R6.
__global__ __launch_bounds__(128) void k2_scores(const float* __restrict__ keys,
                                                 const float* __restrict__ qt,
                                                 float* __restrict__ scp) {
  __shared__ __align__(16) float kb[2][128 * 16];  // 2 x 8 KB
  __shared__ __align__(16) float qb[2][NH * 16];   // 2 x 1 KB
  const int b  = blockIdx.x & 63;
  const int st = (blockIdx.x >> 6) & 7;   // 0..7
  const int mh = blockIdx.x >> 9;         // 0..1
  const int tid = threadIdx.x, w = tid >> 6, l = tid & 63;
  const int hg = l & 3;                   // m-quad stripe
  const int sg = l >> 2;                  // 0..15
  const int s0 = st * 128;
  const size_t rowstride = (size_t)NB * DMODEL;
  const float* kbase = keys + ((size_t)s0 * NB + b) * DMODEL + mh * 512;
  const float* qbase = qt + (size_t)b * NH * DMODEL + mh * 512;
  const int srow  = l >> 2;               // row offset within 16-row unit
  const int sslot = (l & 3) ^ (srow & 3); // pre-swizzled source slot
  const int qh = l >> 2, qj = l & 3;      // q-stage lane mapping

#define K2_STAGE(buf_, ch_) do {                                              \
    _Pragma("unroll")                                                         \
    for (int i_ = 0; i_ < 4; ++i_) {                                          \
      const int u_ = w * 4 + i_;                                              \
      const int row_ = u_ * 16 + srow;                                        \
      gload16(kbase + (size_t)row_ * rowstride + (ch_) * 16 + sslot * 4,      \
              &kb[buf_][u_ * 256]);                                           \
    }                                                                         \
    if (w == 0)                                                               \
      gload16(qbase + (size_t)qh * DMODEL + (ch_) * 16 + qj * 4,              \
              &qb[buf_][0]);                                                  \
  } while (0)

  float acc[4][NH];
#pragma unroll
  for (int si = 0; si < 4; ++si)
#pragma unroll
    for (int hh = 0; hh < NH; ++hh) acc[si][hh] = 0.f;
  const int sl0 = w * 64 + sg;  // local s = sl0 + si*16

  K2_STAGE(0, 0);
  __syncthreads();  // drain prologue stage
  for (int ch = 0; ch < 32; ++ch) {
    const int buf = ch & 1;
    if (ch + 1 < 32) K2_STAGE(buf ^ 1, ch + 1);  // issue-early: overlaps compute
    float4 kv[4];
#pragma unroll
    for (int si = 0; si < 4; ++si) {
      const int s = sl0 + si * 16;
      kv[si] = *reinterpret_cast<const float4*>(&kb[buf][s * 16 + ((hg ^ (s & 3)) << 2)]);
    }
#pragma unroll
    for (int hh = 0; hh < NH; ++hh) {
      float4 q = *reinterpret_cast<const float4*>(&qb[buf][hh * 16 + hg * 4]);
      DOT4_ACC(acc[0][hh], kv[0], q);
      DOT4_ACC(acc[1][hh], kv[1], q);
      DOT4_ACC(acc[2][hh], kv[2], q);
      DOT4_ACC(acc[3][hh], kv[3], q);
    }
    __syncthreads();  // drains next-chunk loads; protects buf for overwrite
  }
#undef K2_STAGE
  // fold the 4 m-stripes within each lane-quad
#pragma unroll
  for (int si = 0; si < 4; ++si)
#pragma unroll
    for (int hh = 0; hh < NH; ++hh) {
      acc[si][hh] += __shfl_xor(acc[si][hh], 1, 64);
      acc[si][hh] += __shfl_xor(acc[si][hh], 2, 64);
    }
  const float scale = 0.125f;  // 1/sqrt(64); linear -> distributes over m-halves
  float* plane = scp + (size_t)mh * NB * NH * SLEN;
#pragma unroll
  for (int j = 0; j < 4; ++j) {
#pragma unroll
    for (int si = 0; si < 4; ++si) {
      float r = hg == 0 ? acc[si][j] : hg == 1 ? acc[si][4 + j]
              : hg == 2 ? acc[si][8 + j] : acc[si][12 + j];
      plane[((size_t)b * NH + hg * 4 + j) * SLEN + s0 + sl0 + si * 16] = r * scale;
    }
  }
}

// Softmax over s: sums the two partial-score planes, softmax, writes plane0.
__global__ __launch_bounds__(256) void k_sm(float* __restrict__ sc0,
                                            const float* __restrict__ sc1) {
  __shared__ float red[8];
  const int tid = threadIdx.x, w = tid >> 6, l = tid & 63;
  float* p0 = sc0 + (size_t)blockIdx.x * SLEN;
  const float* p1 = sc1 + (size_t)blockIdx.x * SLEN;
  float4 xa = reinterpret_cast<const float4*>(p0)[tid];
  float4 xb = reinterpret_cast<const float4*>(p1)[tid];
  float4 x = make_float4(xa.x + xb.x, xa.y + xb.y, xa.z + xb.z, xa.w + xb.w);
  float mx = fmaxf(fmaxf(x.x, x.y), fmaxf(x.z, x.w));
#pragma unroll
  for (int off = 32; off; off >>= 1) mx = fmaxf(mx, __shfl_xor(mx, off, 64));
  if (l == 0) red[w] = mx;
  __syncthreads();
  mx = fmaxf(fmaxf(red[0], red[1]), fmaxf(red[2], red[3]));
  float4 e;
  e.x = __expf(x.x - mx); e.y = __expf(x.y - mx);
  e.z = __expf(x.z - mx); e.w = __expf(x.w - mx);
  float sum = e.x + e.y + e.z + e.w;
  sum = wred_sum(sum);
  if (l == 0) red[4 + w] = sum;
  __syncthreads();
  sum = red[4] + red[5] + red[6] + red[7];
  const float inv = 1.f / sum;
  e.x *= inv; e.y *= inv; e.z *= inv; e.w *= inv;
  reinterpret_cast<float4*>(p0)[tid] = e;
}

// K3 v7: partial c[ch][b][h][m] = sum_{s in chunk} attn[b][h][s]*values[s][b][m].
// DOUBLE-BUFFERED: stage the next 4 value-rows (16 KB) via global_load_lds
// BEFORE computing the current 4 rows; one barrier per group. attn chunk in LDS
// (wave-uniform broadcast reads). 256 thr; LDS 36 KB -> 4 blocks/CU.
template <int NCH>
__global__ __launch_bounds__(256) void k3_cpart(const float* __restrict__ values,
                                                const float* __restrict__ attn,
                                                float* __restrict__ cp) {
  constexpr int SC = SLEN / NCH;
  __shared__ __align__(16) float vb[2][4][DMODEL];  // 32 KB
  __shared__ __align__(16) float al[NH][SC];
  const int b = blockIdx.x & 63;
  const int ch = blockIdx.x >> 6;
  const int s0 = ch * SC;
  const int tid = threadIdx.x, w = tid >> 6, l = tid & 63;
  for (int f = tid; f < NH * (SC / 4); f += 256) {
    int hh = f / (SC / 4), c4 = (f % (SC / 4)) * 4;
    *reinterpret_cast<float4*>(&al[hh][c4]) = *reinterpret_cast<const float4*>(
        attn + ((size_t)b * NH + hh) * SLEN + s0 + c4);
  }
  const int m4 = tid * 4;
  float4 acc[NH];
#pragma unroll
  for (int i = 0; i < NH; ++i) acc[i] = make_float4(0.f, 0.f, 0.f, 0.f);
  const size_t rowstride = (size_t)NB * DMODEL;
  const float* vbase = values + ((size_t)s0 * NB + b) * DMODEL;

#define K3_STAGE(buf_, g_) do {                                               \
    const float* rg_ = vbase + (size_t)((g_) * 4 + w) * rowstride;            \
    _Pragma("unroll")                                                         \
    for (int j_ = 0; j_ < 4; ++j_)                                            \
      gload16(rg_ + j_ * 256 + l * 4, &vb[buf_][w][j_ * 256]);                \
  } while (0)

  K3_STAGE(0, 0);
  __syncthreads();  // drains prologue stage; also covers al
  for (int g = 0; g < SC / 4; ++g) {
    const int buf = g & 1;
    if (g + 1 < SC / 4) K3_STAGE(buf ^ 1, g + 1);  // issue-early
    float4 v0 = *reinterpret_cast<const float4*>(&vb[buf][0][m4]);
    float4 v1 = *reinterpret_cast<const float4*>(&vb[buf][1][m4]);
    float4 v2 = *reinterpret_cast<const float4*>(&vb[buf][2][m4]);
    float4 v3 = *reinterpret_cast<const float4*>(&vb[buf][3][m4]);
#pragma unroll
    for (int hh = 0; hh < NH; ++hh) {
      float4 av = *reinterpret_cast<const float4*>(&al[hh][g * 4]);  // broadcast
      FMA4_BCAST(acc[hh], av, v0, v1, v2, v3);
    }
    __syncthreads();  // drains next-group loads; protects buf for overwrite
  }
#undef K3_STAGE
#pragma unroll
  for (int hh = 0; hh < NH; ++hh)
    *reinterpret_cast<float4*>(cp + (((size_t)ch * NB + b) * NH + hh) * DMODEL + m4) = acc[hh];
}

// K4: out[b][h*64+d] = sum_m Wk[h*64+d][m] * (sum_ch cp[ch][b][h][m]).
template <int NCH>
__global__ __launch_bounds__(256) void k4_out(const float* __restrict__ cp,
                                              const float* __restrict__ Wk,
                                              float* __restrict__ out) {
  __shared__ __align__(16) float cl[4 * DMODEL];
  const int h = blockIdx.x & 15;
  const int b0 = (blockIdx.x >> 4) * 4;
  const int tid = threadIdx.x, w = tid >> 6, l = tid & 63;
  for (int f = tid; f < 4 * DMODEL / 4; f += 256) {
    int bi = f >> 8, m4 = (f & 255) * 4;
    float4 s = make_float4(0.f, 0.f, 0.f, 0.f);
#pragma unroll
    for (int ch = 0; ch < NCH; ++ch) {
      float4 t = *reinterpret_cast<const float4*>(
          cp + (((size_t)ch * NB + b0 + bi) * NH + h) * DMODEL + m4);
      s.x += t.x; s.y += t.y; s.z += t.z; s.w += t.w;
    }
    *reinterpret_cast<float4*>(&cl[bi * DMODEL + m4]) = s;
  }
  __syncthreads();
  float4 c[4][4];
#pragma unroll
  for (int bi = 0; bi < 4; ++bi)
#pragma unroll
    for (int k = 0; k < 4; ++k)
      c[bi][k] = *reinterpret_cast<const float4*>(&cl[bi * DMODEL + l * 16 + k * 4]);
  for (int jj = 0; jj < 16; ++jj) {
    const int d = w * 16 + jj;
    const float4* wr = reinterpret_cast<const float4*>(Wk + (size_t)(h * HD + d) * DMODEL) + l * 4;
    const float4 w0 = wr[0], w1 = wr[1], w2 = wr[2], w3 = wr[3];
#pragma unroll
    for (int bi = 0; bi < 4; ++bi) {
      float s = 0.f;
      DOT4_ACC(s, w0, c[bi][0]); DOT4_ACC(s, w1, c[bi][1]);
      DOT4_ACC(s, w2, c[bi][2]); DOT4_ACC(s, w3, c[bi][3]);
      s = wred_sum(s);
      if (l == 0) out[(size_t)(b0 + bi) * (NH * HD) + h * HD + d] = s;
    }
  }
}

extern "C" void kernel_launch(void* const* d_in, const int* in_sizes, int n_in,
                              void* d_out, int out_size, void* d_ws, size_t ws_size,
                              hipStream_t stream) {
  const float* query  = (const float*)d_in[0];
  const float* keys   = (const float*)d_in[1];
  const float* values = (const float*)d_in[2];
  const float* Wq     = (const float*)d_in[3];
  const float* Wk     = (const float*)d_in[4];
  float* out = (float*)d_out;

  float* W   = (float*)d_ws;
  float* qp  = W;                                   // 64*1024
  float* qt  = qp + (size_t)NB * DMODEL;            // 64*16*1024
  float* sc0 = qt + (size_t)NB * NH * DMODEL;       // partial m-half 0 -> attn
  float* sc1 = sc0 + (size_t)NB * NH * SLEN;        // partial m-half 1
  float* cp  = sc1 + (size_t)NB * NH * SLEN;        // NCH*64*16*1024

  const size_t base_floats = (size_t)NB * DMODEL + (size_t)NB * NH * DMODEL
                           + 2 * (size_t)NB * NH * SLEN;

  k0_qp<<<256, 256, 0, stream>>>(query, Wq, qp);
  k1_qt<<<128, 256, 0, stream>>>(qp, Wk, qt);
  k2_scores<<<1024, 128, 0, stream>>>(keys, qt, sc0);  // writes sc0 (mh=0) and sc1 (mh=1)
  k_sm<<<NB * NH, 256, 0, stream>>>(sc0, sc1);

  const size_t chunk_floats = (size_t)NB * NH * DMODEL;
  if (ws_size >= (base_floats + 16 * chunk_floats) * sizeof(float)) {
    k3_cpart<16><<<16 * NB, 256, 0, stream>>>(values, sc0, cp);
    k4_out<16><<<NH * (NB / 4), 256, 0, stream>>>(cp, Wk, out);
  } else if (ws_size >= (base_floats + 8 * chunk_floats) * sizeof(float)) {
    k3_cpart<8><<<8 * NB, 256, 0, stream>>>(values, sc0, cp);
    k4_out<8><<<NH * (NB / 4), 256, 0, stream>>>(cp, Wk, out);
  } else {
    k3_cpart<4><<<4 * NB, 256, 0, stream>>>(values, sc0, cp);
    k4_out<4><<<NH * (NB / 4), 256, 0, stream>>>(cp, Wk, out);
  }
}

// Round 8
// 244.545 us; speedup vs baseline: 1.0445x; 1.0229x over previous
//
#include <hip/hip_runtime.h>
#include <cstddef>
#include <cstdint>

#define NH 16
#define HD 64
#define SLEN 1024
#define NB 64
#define DMODEL 1024

#define DOT4_ACC(acc, k, q) \
  acc = fmaf((k).x, (q).x, fmaf((k).y, (q).y, fmaf((k).z, (q).z, fmaf((k).w, (q).w, (acc)))))

#define FMA4_BCAST(accv, qv, w0_, w1_, w2_, w3_) do { \
  (accv).x = fmaf((qv).x, (w0_).x, fmaf((qv).y, (w1_).x, fmaf((qv).z, (w2_).x, fmaf((qv).w, (w3_).x, (accv).x)))); \
  (accv).y = fmaf((qv).x, (w0_).y, fmaf((qv).y, (w1_).y, fmaf((qv).z, (w2_).y, fmaf((qv).w, (w3_).y, (accv).y)))); \
  (accv).z = fmaf((qv).x, (w0_).z, fmaf((qv).y, (w1_).z, fmaf((qv).z, (w2_).z, fmaf((qv).w, (w3_).z, (accv).z)))); \
  (accv).w = fmaf((qv).x, (w0_).w, fmaf((qv).y, (w1_).w, fmaf((qv).z, (w2_).w, fmaf((qv).w, (w3_).w, (accv).w)))); \
} while (0)

__device__ __forceinline__ float wred_sum(float v) {
#pragma unroll
  for (int off = 32; off; off >>= 1) v += __shfl_xor(v, off, 64);
  return v;
}

// Async global->LDS, 16B per lane. LDS dest = wave-uniform base + lane*16;
// global source address is per-lane.
__device__ __forceinline__ void gload16(const float* g, float* lds_base) {
  __builtin_amdgcn_global_load_lds(
      (const __attribute__((address_space(1))) void*)g,
      (__attribute__((address_space(3))) void*)lds_base, 16, 0, 0);
}

// K0: qp[b][j] = sum_c query[b][c] * Wq[j][c].
__global__ __launch_bounds__(256) void k0_qp(const float* __restrict__ query,
                                             const float* __restrict__ Wq,
                                             float* __restrict__ qp) {
  const int tid = threadIdx.x;
  const int w = tid >> 6, l = tid & 63;
  const int j = blockIdx.x * 4 + w;  // 0..1023
  const float4* wr = reinterpret_cast<const float4*>(Wq + (size_t)j * DMODEL) + l * 4;
  const float4 w0 = wr[0], w1 = wr[1], w2 = wr[2], w3 = wr[3];
  for (int b = 0; b < NB; ++b) {
    const float4* qr = reinterpret_cast<const float4*>(query + (size_t)b * DMODEL) + l * 4;
    float4 q0 = qr[0], q1 = qr[1], q2 = qr[2], q3 = qr[3];
    float s = 0.f;
    DOT4_ACC(s, w0, q0); DOT4_ACC(s, w1, q1); DOT4_ACC(s, w2, q2); DOT4_ACC(s, w3, q3);
    s = wred_sum(s);
    if (l == 0) qp[(size_t)b * DMODEL + j] = s;
  }
}

// K1: qt[b][h][m] = sum_d qp[b][h*64+d] * Wk[h*64+d][m].
__global__ __launch_bounds__(256) void k1_qt(const float* __restrict__ qp,
                                             const float* __restrict__ Wk,
                                             float* __restrict__ qt) {
  __shared__ __align__(16) float qpl[8][HD];
  const int h = blockIdx.x & 15;
  const int b0 = (blockIdx.x >> 4) * 8;
  const int tid = threadIdx.x;
  for (int f = tid; f < 8 * HD; f += 256) {
    int bi = f >> 6, d = f & 63;
    qpl[bi][d] = qp[(size_t)(b0 + bi) * DMODEL + h * HD + d];
  }
  __syncthreads();
  const int m4 = tid * 4;
  float4 acc[8];
#pragma unroll
  for (int i = 0; i < 8; ++i) acc[i] = make_float4(0.f, 0.f, 0.f, 0.f);
  const float* wbase = Wk + (size_t)(h * HD) * DMODEL + m4;
  for (int d = 0; d < HD; d += 4) {
    float4 wk0 = *reinterpret_cast<const float4*>(wbase + (size_t)(d + 0) * DMODEL);
    float4 wk1 = *reinterpret_cast<const float4*>(wbase + (size_t)(d + 1) * DMODEL);
    float4 wk2 = *reinterpret_cast<const float4*>(wbase + (size_t)(d + 2) * DMODEL);
    float4 wk3 = *reinterpret_cast<const float4*>(wbase + (size_t)(d + 3) * DMODEL);
#pragma unroll
    for (int bi = 0; bi < 8; ++bi) {
      float4 q = *reinterpret_cast<const float4*>(&qpl[bi][d]);
      FMA4_BCAST(acc[bi], q, wk0, wk1, wk2, wk3);
    }
  }
#pragma unroll
  for (int bi = 0; bi < 8; ++bi)
    *reinterpret_cast<float4*>(qt + ((size_t)(b0 + bi) * NH + h) * DMODEL + m4) = acc[bi];
}

// K2 v8: partial scores over an m-half; 256B-PER-ROW-VISIT staging.
// Block = 256 thr (4 waves) = (b, st: 64-s tile, mh: m-half). Chunk = 64 floats
// (256B) per key row x 64 rows = 16 KB, double-buffered, issue-early before
// compute (one barrier per chunk). The 4x wider per-row DRAM visit (vs 64B in
// v6/v7) is the experiment: page-activation overhead /4.
// kb XOR-swizzled via pre-swizzled GLOBAL source slot (LDS dest linear):
// stored[row][slot] = src[row][slot ^ (row&7)]; read col = c ^ ((row&7)<<2).
// Wave w owns h-quad w*4..w*4+3; lane: hg=l&3 (m-stripe), sg=l>>2; 4 si s-rows.
__global__ __launch_bounds__(256) void k2_scores(const float* __restrict__ keys,
                                                 const float* __restrict__ qt,
                                                 float* __restrict__ scp) {
  __shared__ __align__(16) float kb[2][64 * 64];  // 2 x 16 KB
  __shared__ __align__(16) float qb[2][NH * 64];  // 2 x 4 KB
  const int b  = blockIdx.x & 63;
  const int st = (blockIdx.x >> 6) & 15;  // 0..15
  const int mh = blockIdx.x >> 10;        // 0..1
  const int tid = threadIdx.x, w = tid >> 6, l = tid & 63;
  const int hg = l & 3;                   // m-quad stripe
  const int sg = l >> 2;                  // 0..15
  const int s0 = st * 64;
  const size_t rowstride = (size_t)NB * DMODEL;
  const float* kbase = keys + ((size_t)s0 * NB + b) * DMODEL + mh * 512;
  const float* qbase = qt + (size_t)b * NH * DMODEL + mh * 512;
  const int srow_lo = l >> 4;             // row-in-4-group for kb stage
  const int sslot   = l & 15;             // 16B slot within 256B row
  const int qh = w * 4 + (l >> 4);        // head staged by this lane

#define K2_STAGE(buf_, ch_) do {                                               \
    _Pragma("unroll")                                                          \
    for (int i_ = 0; i_ < 4; ++i_) {                                           \
      const int row_ = i_ * 16 + w * 4 + srow_lo;                              \
      gload16(kbase + (size_t)row_ * rowstride + (ch_) * 64 +                  \
                  ((sslot ^ (row_ & 7)) << 2),                                 \
              &kb[buf_][(i_ * 16 + w * 4) * 64]);                              \
    }                                                                          \
    gload16(qbase + (size_t)qh * DMODEL + (ch_) * 64 + (sslot << 2),           \
            &qb[buf_][w * 4 * 64]);                                            \
  } while (0)

  float acc[4][4];  // [si][hh]
#pragma unroll
  for (int si = 0; si < 4; ++si)
#pragma unroll
    for (int hh = 0; hh < 4; ++hh) acc[si][hh] = 0.f;

  K2_STAGE(0, 0);
  __syncthreads();  // drain prologue stage
  for (int ch = 0; ch < 8; ++ch) {
    const int buf = ch & 1;
    if (ch + 1 < 8) K2_STAGE(buf ^ 1, ch + 1);  // issue-early: overlaps compute
    float4 kv[4][4];
#pragma unroll
    for (int si = 0; si < 4; ++si) {
      const int row = si * 16 + sg;
      const int sw = (row & 7) << 2;
#pragma unroll
      for (int j = 0; j < 4; ++j)
        kv[si][j] = *reinterpret_cast<const float4*>(
            &kb[buf][row * 64 + ((hg * 4 + 16 * j) ^ sw)]);
    }
#pragma unroll
    for (int hh = 0; hh < 4; ++hh) {
      const float* qrow = &qb[buf][(w * 4 + hh) * 64 + hg * 4];
      float4 q0 = *reinterpret_cast<const float4*>(qrow);
      float4 q1 = *reinterpret_cast<const float4*>(qrow + 16);
      float4 q2 = *reinterpret_cast<const float4*>(qrow + 32);
      float4 q3 = *reinterpret_cast<const float4*>(qrow + 48);
#pragma unroll
      for (int si = 0; si < 4; ++si) {
        DOT4_ACC(acc[si][hh], kv[si][0], q0);
        DOT4_ACC(acc[si][hh], kv[si][1], q1);
        DOT4_ACC(acc[si][hh], kv[si][2], q2);
        DOT4_ACC(acc[si][hh], kv[si][3], q3);
      }
    }
    __syncthreads();  // drains next-chunk loads; protects buf for overwrite
  }
#undef K2_STAGE
  // fold the 4 m-stripes within each lane-quad
#pragma unroll
  for (int si = 0; si < 4; ++si)
#pragma unroll
    for (int hh = 0; hh < 4; ++hh) {
      acc[si][hh] += __shfl_xor(acc[si][hh], 1, 64);
      acc[si][hh] += __shfl_xor(acc[si][hh], 2, 64);
    }
  const float scale = 0.125f;  // 1/sqrt(64); linear -> distributes over m-halves
  float* plane = scp + (size_t)mh * NB * NH * SLEN;
#pragma unroll
  for (int si = 0; si < 4; ++si) {
    // lane hg writes head w*4+hg (static acc selection, no scratch)
    float r = hg == 0 ? acc[si][0] : hg == 1 ? acc[si][1]
            : hg == 2 ? acc[si][2] : acc[si][3];
    plane[((size_t)b * NH + w * 4 + hg) * SLEN + s0 + si * 16 + sg] = r * scale;
  }
}

// Softmax over s: sums the two partial-score planes, softmax, writes plane0.
__global__ __launch_bounds__(256) void k_sm(float* __restrict__ sc0,
                                            const float* __restrict__ sc1) {
  __shared__ float red[8];
  const int tid = threadIdx.x, w = tid >> 6, l = tid & 63;
  float* p0 = sc0 + (size_t)blockIdx.x * SLEN;
  const float* p1 = sc1 + (size_t)blockIdx.x * SLEN;
  float4 xa = reinterpret_cast<const float4*>(p0)[tid];
  float4 xb = reinterpret_cast<const float4*>(p1)[tid];
  float4 x = make_float4(xa.x + xb.x, xa.y + xb.y, xa.z + xb.z, xa.w + xb.w);
  float mx = fmaxf(fmaxf(x.x, x.y), fmaxf(x.z, x.w));
#pragma unroll
  for (int off = 32; off; off >>= 1) mx = fmaxf(mx, __shfl_xor(mx, off, 64));
  if (l == 0) red[w] = mx;
  __syncthreads();
  mx = fmaxf(fmaxf(red[0], red[1]), fmaxf(red[2], red[3]));
  float4 e;
  e.x = __expf(x.x - mx); e.y = __expf(x.y - mx);
  e.z = __expf(x.z - mx); e.w = __expf(x.w - mx);
  float sum = e.x + e.y + e.z + e.w;
  sum = wred_sum(sum);
  if (l == 0) red[4 + w] = sum;
  __syncthreads();
  sum = red[4] + red[5] + red[6] + red[7];
  const float inv = 1.f / sum;
  e.x *= inv; e.y *= inv; e.z *= inv; e.w *= inv;
  reinterpret_cast<float4*>(p0)[tid] = e;
}

// K3 v7 (unchanged): partial c[ch][b][h][m] = sum_{s in chunk} attn*values.
// DOUBLE-BUFFERED full-row staging via global_load_lds; attn chunk in LDS.
template <int NCH>
__global__ __launch_bounds__(256) void k3_cpart(const float* __restrict__ values,
                                                const float* __restrict__ attn,
                                                float* __restrict__ cp) {
  constexpr int SC = SLEN / NCH;
  __shared__ __align__(16) float vb[2][4][DMODEL];  // 32 KB
  __shared__ __align__(16) float al[NH][SC];
  const int b = blockIdx.x & 63;
  const int ch = blockIdx.x >> 6;
  const int s0 = ch * SC;
  const int tid = threadIdx.x, w = tid >> 6, l = tid & 63;
  for (int f = tid; f < NH * (SC / 4); f += 256) {
    int hh = f / (SC / 4), c4 = (f % (SC / 4)) * 4;
    *reinterpret_cast<float4*>(&al[hh][c4]) = *reinterpret_cast<const float4*>(
        attn + ((size_t)b * NH + hh) * SLEN + s0 + c4);
  }
  const int m4 = tid * 4;
  float4 acc[NH];
#pragma unroll
  for (int i = 0; i < NH; ++i) acc[i] = make_float4(0.f, 0.f, 0.f, 0.f);
  const size_t rowstride = (size_t)NB * DMODEL;
  const float* vbase = values + ((size_t)s0 * NB + b) * DMODEL;

#define K3_STAGE(buf_, g_) do {                                               \
    const float* rg_ = vbase + (size_t)((g_) * 4 + w) * rowstride;            \
    _Pragma("unroll")                                                         \
    for (int j_ = 0; j_ < 4; ++j_)                                            \
      gload16(rg_ + j_ * 256 + l * 4, &vb[buf_][w][j_ * 256]);                \
  } while (0)

  K3_STAGE(0, 0);
  __syncthreads();  // drains prologue stage; also covers al
  for (int g = 0; g < SC / 4; ++g) {
    const int buf = g & 1;
    if (g + 1 < SC / 4) K3_STAGE(buf ^ 1, g + 1);  // issue-early
    float4 v0 = *reinterpret_cast<const float4*>(&vb[buf][0][m4]);
    float4 v1 = *reinterpret_cast<const float4*>(&vb[buf][1][m4]);
    float4 v2 = *reinterpret_cast<const float4*>(&vb[buf][2][m4]);
    float4 v3 = *reinterpret_cast<const float4*>(&vb[buf][3][m4]);
#pragma unroll
    for (int hh = 0; hh < NH; ++hh) {
      float4 av = *reinterpret_cast<const float4*>(&al[hh][g * 4]);  // broadcast
      FMA4_BCAST(acc[hh], av, v0, v1, v2, v3);
    }
    __syncthreads();  // drains next-group loads; protects buf for overwrite
  }
#undef K3_STAGE
#pragma unroll
  for (int hh = 0; hh < NH; ++hh)
    *reinterpret_cast<float4*>(cp + (((size_t)ch * NB + b) * NH + hh) * DMODEL + m4) = acc[hh];
}

// K4: out[b][h*64+d] = sum_m Wk[h*64+d][m] * (sum_ch cp[ch][b][h][m]).
template <int NCH>
__global__ __launch_bounds__(256) void k4_out(const float* __restrict__ cp,
                                              const float* __restrict__ Wk,
                                              float* __restrict__ out) {
  __shared__ __align__(16) float cl[4 * DMODEL];
  const int h = blockIdx.x & 15;
  const int b0 = (blockIdx.x >> 4) * 4;
  const int tid = threadIdx.x, w = tid >> 6, l = tid & 63;
  for (int f = tid; f < 4 * DMODEL / 4; f += 256) {
    int bi = f >> 8, m4 = (f & 255) * 4;
    float4 s = make_float4(0.f, 0.f, 0.f, 0.f);
#pragma unroll
    for (int ch = 0; ch < NCH; ++ch) {
      float4 t = *reinterpret_cast<const float4*>(
          cp + (((size_t)ch * NB + b0 + bi) * NH + h) * DMODEL + m4);
      s.x += t.x; s.y += t.y; s.z += t.z; s.w += t.w;
    }
    *reinterpret_cast<float4*>(&cl[bi * DMODEL + m4]) = s;
  }
  __syncthreads();
  float4 c[4][4];
#pragma unroll
  for (int bi = 0; bi < 4; ++bi)
#pragma unroll
    for (int k = 0; k < 4; ++k)
      c[bi][k] = *reinterpret_cast<const float4*>(&cl[bi * DMODEL + l * 16 + k * 4]);
  for (int jj = 0; jj < 16; ++jj) {
    const int d = w * 16 + jj;
    const float4* wr = reinterpret_cast<const float4*>(Wk + (size_t)(h * HD + d) * DMODEL) + l * 4;
    const float4 w0 = wr[0], w1 = wr[1], w2 = wr[2], w3 = wr[3];
#pragma unroll
    for (int bi = 0; bi < 4; ++bi) {
      float s = 0.f;
      DOT4_ACC(s, w0, c[bi][0]); DOT4_ACC(s, w1, c[bi][1]);
      DOT4_ACC(s, w2, c[bi][2]); DOT4_ACC(s, w3, c[bi][3]);
      s = wred_sum(s);
      if (l == 0) out[(size_t)(b0 + bi) * (NH * HD) + h * HD + d] = s;
    }
  }
}

extern "C" void kernel_launch(void* const* d_in, const int* in_sizes, int n_in,
                              void* d_out, int out_size, void* d_ws, size_t ws_size,
                              hipStream_t stream) {
  const float* query  = (const float*)d_in[0];
  const float* keys   = (const float*)d_in[1];
  const float* values = (const float*)d_in[2];
  const float* Wq     = (const float*)d_in[3];
  const float* Wk     = (const float*)d_in[4];
  float* out = (float*)d_out;

  float* W   = (float*)d_ws;
  float* qp  = W;                                   // 64*1024
  float* qt  = qp + (size_t)NB * DMODEL;            // 64*16*1024
  float* sc0 = qt + (size_t)NB * NH * DMODEL;       // partial m-half 0 -> attn
  float* sc1 = sc0 + (size_t)NB * NH * SLEN;        // partial m-half 1
  float* cp  = sc1 + (size_t)NB * NH * SLEN;        // NCH*64*16*1024

  const size_t base_floats = (size_t)NB * DMODEL + (size_t)NB * NH * DMODEL
                           + 2 * (size_t)NB * NH * SLEN;

  k0_qp<<<256, 256, 0, stream>>>(query, Wq, qp);
  k1_qt<<<128, 256, 0, stream>>>(qp, Wk, qt);
  k2_scores<<<2048, 256, 0, stream>>>(keys, qt, sc0);  // writes sc0 (mh=0) / sc1 (mh=1)
  k_sm<<<NB * NH, 256, 0, stream>>>(sc0, sc1);

  const size_t chunk_floats = (size_t)NB * NH * DMODEL;
  if (ws_size >= (base_floats + 16 * chunk_floats) * sizeof(float)) {
    k3_cpart<16><<<16 * NB, 256, 0, stream>>>(values, sc0, cp);
    k4_out<16><<<NH * (NB / 4), 256, 0, stream>>>(cp, Wk, out);
  } else if (ws_size >= (base_floats + 8 * chunk_floats) * sizeof(float)) {
    k3_cpart<8><<<8 * NB, 256, 0, stream>>>(values, sc0, cp);
    k4_out<8><<<NH * (NB / 4), 256, 0, stream>>>(cp, Wk, out);
  } else {
    k3_cpart<4><<<4 * NB, 256, 0, stream>>>(values, sc0, cp);
    k4_out<4><<<NH * (NB / 4), 256, 0, stream>>>(cp, Wk, out);
  }
}